// Round 23
// baseline (140.455 us; speedup 1.0000x reference)
//
#include <hip/hip_runtime.h>
#include <float.h>

#define BB 4
#define PP 1024
#define DD 1024
#define RR 256
#define SSZ 256
#define KT 4
#define EE 4096
#define NPAIR 3

typedef float  f32x4  __attribute__((ext_vector_type(4)));
typedef short  short8 __attribute__((ext_vector_type(8)));

#define MFMA16(a,b,c) __builtin_amdgcn_mfma_f32_16x16x32_bf16((a),(b),(c),0,0,0)

// ---- float-region offsets (in floats) ----
#define OFF_NE    ((size_t)0)         // BB*EE
#define OFF_RR_T  ((size_t)16384)     // BB*RR
#define OFF_RR_S  ((size_t)17408)
#define OFF_HH    ((size_t)18432)     // BB*RR*KT
#define OFF_RH_T  ((size_t)22528)
#define OFF_RH_S  ((size_t)26624)
#define OFF_SS_T  ((size_t)30720)     // NPAIR*BB*SSZ
#define OFF_SS_S  ((size_t)33792)
#define OFF_TOPK  ((size_t)36864)     // BB*RR*KT ints
#define OFF_ACC   ((size_t)40960)     // double + int counter (16 B zeroed)
#define OFF_CAND  ((size_t)45056)     // BB*RR*64*4 float2 = 524288 floats
#define FLOAT_END ((size_t)569344)

// ---- ushort (bf16 hi) regions, K-major 16-row-group layout ----
// group g: [32 k-chunks][16 rows][4 swizzled 16B slots]
//   elem (row R, k): g=R>>4, rr=R&15, c=k>>5, s=(k>>3)&3, slot=s^((rr>>1)&3)
//   ushort off = base + g*16384 + c*512 + rr*32 + slot*8 + (k&7)
#define U_REF_T ((size_t)0)           // BB*RR*DD
#define U_REF_S ((size_t)2097152)
#define U_SIMH  ((size_t)4194304)     // BB*RR*KT*DD
#define U_SH_T  ((size_t)8388608)     // NPAIR*BB*SSZ*DD
#define U_SH_S  ((size_t)11534336)
#define U_EXT   ((size_t)14680064)    // BB*EE*DD
// end 31457280 ushorts; total ws ~65.2 MB

__device__ inline float block_sum256(float v, float* sb) {
  v += __shfl_down(v, 32); v += __shfl_down(v, 16);
  v += __shfl_down(v, 8);  v += __shfl_down(v, 4);
  v += __shfl_down(v, 2);  v += __shfl_down(v, 1);
  int lane = threadIdx.x & 63, wid = threadIdx.x >> 6;
  if (lane == 0) sb[wid] = v;
  __syncthreads();
  float r = 0.f;
  if (threadIdx.x < 4) r = sb[threadIdx.x];
  r += __shfl_down(r, 2); r += __shfl_down(r, 1);
  __syncthreads();
  return r;   // valid on thread 0
}

__device__ inline float dot4(const float4& a, const float4& b) {
  return a.x*b.x + a.y*b.y + a.z*b.z + a.w*b.w;
}

// round-to-nearest-even bf16
__device__ inline unsigned short bhi(float x) {
  unsigned u = __float_as_uint(x);
  return (unsigned short)((u + 0x7fffu + ((u >> 16) & 1u)) >> 16);
}
__device__ inline ushort4 h4of(float4 f) {
  return make_ushort4(bhi(f.x), bhi(f.y), bhi(f.z), bhi(f.w));
}

// writer offset for thread t (t=0..255, k=4t..4t+3) of global row R
__device__ inline size_t wofs(size_t base, int R, int t) {
  int rr = R & 15;
  int ss = ((t >> 1) & 3) ^ ((rr >> 1) & 3);
  return base + (size_t)(R >> 4)*16384 + (size_t)(t >> 3)*512
       + rr*32 + ss*8 + (t & 1)*4;
}

// ---- fused prep: gather_ref (0..1023) | ne (1024..17407) | ss (17408..20479) ----
__global__ __launch_bounds__(256) void k_prep(const float* __restrict__ T,
                                              const float* __restrict__ Sf,
                                              const int* __restrict__ ref_perm,
                                              const int* __restrict__ shared_perm,
                                              float* __restrict__ ws) {
  __shared__ float sb[4];
  ushort* uws = (ushort*)(ws + FLOAT_END);
  int blk = blockIdx.x;
  int t = threadIdx.x;
  if (blk < 1024) {
    int b = blk >> 8, r = blk & 255;
    int pos = ref_perm[r];
    const float4* ts = (const float4*)(T  + ((size_t)(b*8 + 0)*PP + pos)*DD);
    const float4* sv = (const float4*)(Sf + ((size_t)(b*4 + 0)*PP + pos)*DD);
    float4 a = ts[t], c = sv[t];
    int R = b*RR + r;
    *(ushort4*)(uws + wofs(U_REF_T, R, t)) = h4of(a);
    *(ushort4*)(uws + wofs(U_REF_S, R, t)) = h4of(c);
    float r1 = block_sum256(dot4(a, a), sb);
    float r2 = block_sum256(dot4(c, c), sb);
    if (t == 0) {
      ws[OFF_RR_T + R] = r1;
      ws[OFF_RR_S + R] = r2;
    }
  } else if (blk < 17408) {
    int i = blk - 1024;
    int b = i >> 12, e = i & 4095;
    int f = 1 + 2*(e >> 10);
    int pos = e & 1023;
    const float4* src = (const float4*)(T + ((size_t)(b*8 + f)*PP + pos)*DD);
    float4 a = src[t];
    *(ushort4*)(uws + wofs(U_EXT, b*EE + e, t)) = h4of(a);
    float tot = block_sum256(dot4(a, a), sb);
    if (t == 0) ws[OFF_NE + (size_t)b*EE + e] = fmaxf(sqrtf(tot), 1e-12f);
  } else {
    int idx = blk - 17408;                 // z*SSZ + s
    int p = idx / (BB*SSZ);
    int b = (idx / SSZ) % BB;
    int s = idx % SSZ;
    int pos = shared_perm[s];
    int ti = 2*(p + 1), si = p + 1;
    const float4* tr = (const float4*)(T  + ((size_t)(b*8 + ti)*PP + pos)*DD);
    const float4* sr = (const float4*)(Sf + ((size_t)(b*4 + si)*PP + pos)*DD);
    float4 a = tr[t], c = sr[t];
    *(ushort4*)(uws + wofs(U_SH_T, idx, t)) = h4of(a);
    *(ushort4*)(uws + wofs(U_SH_S, idx, t)) = h4of(c);
    float r1 = block_sum256(dot4(a, a), sb);
    float r2 = block_sum256(dot4(c, c), sb);
    if (t == 0) { ws[OFF_SS_T + idx] = r1; ws[OFF_SS_S + idx] = r2; }
  }
}

// ---- sim GEMM: BARRIER-FREE. One wave per (r16, e64) tile. ----
__global__ __launch_bounds__(256) void k_sim(float* __restrict__ ws) {
  __shared__ float simv[4][16][68];
  const ushort* uws = (const ushort*)(ws + FLOAT_END);
  int d = blockIdx.x;
  int u8 = d & 7, q = d >> 3;          // q 0..127
  int b = u8 >> 1, eh = u8 & 1;
  int eb = eh*32 + (q >> 2);           // e64-block 0..63
  int rgq = q & 3;
  int tid = threadIdx.x;
  int w = tid >> 6, lane = tid & 63;
  int rg = rgq*4 + w;                  // r16-group 0..15
  int r0 = rg*16, e0 = eb*64;
  int l15 = lane & 15, lq = (lane >> 4) & 3;
  int laneoff = l15*32 + ((lq ^ ((l15 >> 1) & 3)))*8;

  const ushort* pA = uws + U_REF_T + ((size_t)((b*RR + r0) >> 4))*16384 + laneoff;
  const ushort* pB0 = uws + U_EXT + ((size_t)((b*EE + e0) >> 4) + 0)*16384 + laneoff;
  const ushort* pB1 = uws + U_EXT + ((size_t)((b*EE + e0) >> 4) + 1)*16384 + laneoff;
  const ushort* pB2 = uws + U_EXT + ((size_t)((b*EE + e0) >> 4) + 2)*16384 + laneoff;
  const ushort* pB3 = uws + U_EXT + ((size_t)((b*EE + e0) >> 4) + 3)*16384 + laneoff;

  f32x4 acc[4];
#pragma unroll
  for (int j = 0; j < 4; ++j) acc[j] = (f32x4){0.f, 0.f, 0.f, 0.f};

#pragma unroll 4
  for (int c = 0; c < 32; ++c) {
    int o = c*512;
    short8 ah = *(const short8*)(pA + o);
    short8 b0 = *(const short8*)(pB0 + o);
    short8 b1 = *(const short8*)(pB1 + o);
    short8 b2 = *(const short8*)(pB2 + o);
    short8 b3 = *(const short8*)(pB3 + o);
    acc[0] = MFMA16(ah, b0, acc[0]);
    acc[1] = MFMA16(ah, b1, acc[1]);
    acc[2] = MFMA16(ah, b2, acc[2]);
    acc[3] = MFMA16(ah, b3, acc[3]);
  }

  float invs[4];
#pragma unroll
  for (int j = 0; j < 4; ++j)
    invs[j] = 1.f / ws[OFF_NE + (size_t)b*EE + e0 + j*16 + l15];
#pragma unroll
  for (int j = 0; j < 4; ++j)
#pragma unroll
    for (int q2 = 0; q2 < 4; ++q2)
      simv[w][lq*4 + q2][j*16 + l15] = acc[j][q2] * invs[j];
  // same-wave LDS write->read: lgkmcnt ordering only, no barrier needed
  if (lane < 16) {
    float v[4] = {-FLT_MAX, -FLT_MAX, -FLT_MAX, -FLT_MAX};
    int ix[4] = {0x7fffffff, 0x7fffffff, 0x7fffffff, 0x7fffffff};
#pragma unroll 1
    for (int e = 0; e < 64; ++e) {
      float f = simv[w][lane][e];
      if (f > v[3]) {
        int eg = e0 + e;
        if (f > v[0])      { v[3]=v[2]; ix[3]=ix[2]; v[2]=v[1]; ix[2]=ix[1]; v[1]=v[0]; ix[1]=ix[0]; v[0]=f; ix[0]=eg; }
        else if (f > v[1]) { v[3]=v[2]; ix[3]=ix[2]; v[2]=v[1]; ix[2]=ix[1]; v[1]=f; ix[1]=eg; }
        else if (f > v[2]) { v[3]=v[2]; ix[3]=ix[2]; v[2]=f; ix[2]=eg; }
        else               { v[3]=f; ix[3]=eg; }
      }
    }
    float2* cand = (float2*)(ws + OFF_CAND);
    size_t base = (((size_t)(b*RR + r0 + lane))*64 + eb)*4;
#pragma unroll
    for (int k = 0; k < 4; ++k)
      cand[base + k] = make_float2(v[k], __int_as_float(ix[k]));
  }
}

// ---- merged select: top-4 merge + gather + hh/rh dots, one block per (b,r) ----
__global__ __launch_bounds__(256) void k_select(const float* __restrict__ T,
                                                const float* __restrict__ Sf,
                                                const int* __restrict__ ref_perm,
                                                float* __restrict__ ws) {
  __shared__ float rv[256];
  __shared__ int   ri[256];
  __shared__ int   winIdx;
  __shared__ int   sel[4];
  int br = blockIdx.x;
  int tid = threadIdx.x;
  const float2* cand = (const float2*)(ws + OFF_CAND);
  float2 c0 = cand[(size_t)br*256 + tid];
  float v = c0.x;
  int idx = __float_as_int(c0.y);
  int* outi = (int*)(ws + OFF_TOPK) + (size_t)br*KT;
  for (int k = 0; k < KT; ++k) {
    rv[tid] = v; ri[tid] = idx;
    __syncthreads();
    for (int off = 128; off > 0; off >>= 1) {
      if (tid < off) {
        float v2 = rv[tid+off]; int i2 = ri[tid+off];
        if (v2 > rv[tid] || (v2 == rv[tid] && i2 < ri[tid])) { rv[tid] = v2; ri[tid] = i2; }
      }
      __syncthreads();
    }
    if (tid == 0) { outi[k] = ri[0]; winIdx = ri[0]; sel[k] = ri[0]; }
    __syncthreads();
    if (idx == winIdx) v = -FLT_MAX;
    __syncthreads();
  }

  // phase 2: gather 4 selected rows (group g = k), bf16 store + 3 dots each
  int b = br >> 8, r = br & 255;
  int g = tid >> 6, lane = tid & 63;
  int e = sel[g];
  int rpos = ref_perm[r];
  const float4* src = (const float4*)(T + ((size_t)(b*8 + 1 + 2*(e >> 10))*PP + (e & 1023))*DD);
  const float4* rt  = (const float4*)(T  + ((size_t)(b*8 + 0)*PP + rpos)*DD);
  const float4* rs  = (const float4*)(Sf + ((size_t)(b*4 + 0)*PP + rpos)*DD);
  ushort* uws = (ushort*)(ws + FLOAT_END);
  int rowi = br*KT + g;
  float hh = 0.f, rht = 0.f, rhs = 0.f;
#pragma unroll
  for (int i = 0; i < 4; ++i) {
    int t4 = lane*4 + i;               // 0..255
    float4 h = src[t4];
    *(ushort4*)(uws + wofs(U_SIMH, rowi, t4)) = h4of(h);
    float4 a = rt[t4], c = rs[t4];
    hh  += dot4(h, h);
    rht += dot4(h, a);
    rhs += dot4(h, c);
  }
  hh  += __shfl_down(hh, 32);  hh  += __shfl_down(hh, 16);
  hh  += __shfl_down(hh, 8);   hh  += __shfl_down(hh, 4);
  hh  += __shfl_down(hh, 2);   hh  += __shfl_down(hh, 1);
  rht += __shfl_down(rht, 32); rht += __shfl_down(rht, 16);
  rht += __shfl_down(rht, 8);  rht += __shfl_down(rht, 4);
  rht += __shfl_down(rht, 2);  rht += __shfl_down(rht, 1);
  rhs += __shfl_down(rhs, 32); rhs += __shfl_down(rhs, 16);
  rhs += __shfl_down(rhs, 8);  rhs += __shfl_down(rhs, 4);
  rhs += __shfl_down(rhs, 2);  rhs += __shfl_down(rhs, 1);
  if (lane == 0) {
    ws[OFF_HH + rowi]   = hh;
    ws[OFF_RH_T + rowi] = rht;
    ws[OFF_RH_S + rowi] = rhs;
  }
}

// ---- main fused kernel: BARRIER-FREE, s64 per wave, balanced 256x192 ----
// 768 r16xs64 wave-tiles; 3 waves/block, 256 blocks = exactly 1 block/CU.
// u8 = d&7 (XCD pin); t = (d>>3)*3 + w in [0,96): p = t>>5; s64i = (t&31)>>3;
// r16q = t&7; r16i = rhalf*8 + r16q.  Epilogue: 4 s16 passes; k_final fused.
__global__ __launch_bounds__(192) void k_main(float* __restrict__ ws,
                                              double* __restrict__ acc_out,
                                              float* __restrict__ out) {
  __shared__ float Ct[3][80][17];
  __shared__ float Cs2[3][80][17];
  __shared__ float sb[3];
  const ushort* uws = (const ushort*)(ws + FLOAT_END);

  int d = blockIdx.x;
  int u8 = d & 7, q = d >> 3;        // q 0..31
  int b = u8 >> 1, rhalf = u8 & 1;
  int tid = threadIdx.x;
  int w = tid >> 6, lane = tid & 63;
  int t = q*3 + w;                   // 0..95
  int p = t >> 5;
  int rem = t & 31;
  int s64i = rem >> 3, r16q = rem & 7;
  int z = p*4 + b;
  int r16i = rhalf*8 + r16q;
  int r0 = r16i*16, s0 = s64i*64;

  int l15 = lane & 15, lq = (lane >> 4) & 3;
  int laneoff = l15*32 + ((lq ^ ((l15 >> 1) & 3)))*8;

  // fragment pointers (each contiguous 1 KB per k-step)
  const ushort* pa0; const ushort* pa1; const ushort* pa2; const ushort* pa3;
  const ushort* prt; const ushort* prs;
  const ushort* pbt[4]; const ushort* pbs[4];
  {
    size_t gs = (size_t)((b*RR + r0) >> 2);      // simh group base (4 groups)
    pa0 = uws + U_SIMH + (gs + 0)*16384 + laneoff;
    pa1 = uws + U_SIMH + (gs + 1)*16384 + laneoff;
    pa2 = uws + U_SIMH + (gs + 2)*16384 + laneoff;
    pa3 = uws + U_SIMH + (gs + 3)*16384 + laneoff;
    size_t gr = (size_t)((b*RR + r0) >> 4);
    prt = uws + U_REF_T + gr*16384 + laneoff;
    prs = uws + U_REF_S + gr*16384 + laneoff;
    size_t gh = (size_t)((z*SSZ + s0) >> 4);
#pragma unroll
    for (int j = 0; j < 4; ++j) {
      pbt[j] = uws + U_SH_T + (gh + j)*16384 + laneoff;
      pbs[j] = uws + U_SH_S + (gh + j)*16384 + laneoff;
    }
  }

  f32x4 aT0[4], aT1[4], aT2[4], aT3[4], aRT[4];
  f32x4 aS0[4], aS1[4], aS2[4], aS3[4], aRS[4];
#pragma unroll
  for (int h = 0; h < 4; ++h) {
    aT0[h] = aT1[h] = aT2[h] = aT3[h] = aRT[h] = (f32x4){0.f,0.f,0.f,0.f};
    aS0[h] = aS1[h] = aS2[h] = aS3[h] = aRS[h] = (f32x4){0.f,0.f,0.f,0.f};
  }

#pragma unroll 1
  for (int c = 0; c < 32; ++c) {
    int o = c*512;
    short8 a0 = *(const short8*)(pa0 + o);
    short8 a1 = *(const short8*)(pa1 + o);
    short8 a2 = *(const short8*)(pa2 + o);
    short8 a3 = *(const short8*)(pa3 + o);
    short8 rt = *(const short8*)(prt + o);
    short8 rs = *(const short8*)(prs + o);
#pragma unroll
    for (int h = 0; h < 4; ++h) {
      short8 bt = *(const short8*)(pbt[h] + o);
      short8 bs = *(const short8*)(pbs[h] + o);
      aT0[h] = MFMA16(a0, bt, aT0[h]);
      aT1[h] = MFMA16(a1, bt, aT1[h]);
      aT2[h] = MFMA16(a2, bt, aT2[h]);
      aT3[h] = MFMA16(a3, bt, aT3[h]);
      aRT[h] = MFMA16(rt, bt, aRT[h]);
      aS0[h] = MFMA16(a0, bs, aS0[h]);
      aS1[h] = MFMA16(a1, bs, aS1[h]);
      aS2[h] = MFMA16(a2, bs, aS2[h]);
      aS3[h] = MFMA16(a3, bs, aS3[h]);
      aRS[h] = MFMA16(rs, bs, aRS[h]);
    }
  }

  // per-r scalars (h-independent)
  int rl = lane >> 2, sg = lane & 3;
  int r = r0 + rl;
  float rrt = ws[OFF_RR_T + b*RR + r];
  float rrs = ws[OFF_RR_S + b*RR + r];
  float hhk[4], rhtk[4], rhsk[4], ihr_t[4], ihr_s[4];
#pragma unroll
  for (int k = 0; k < 4; ++k) {
    int idx = (b*RR + r)*KT + k;
    hhk[k]  = ws[OFF_HH + idx];
    rhtk[k] = ws[OFF_RH_T + idx];
    rhsk[k] = ws[OFF_RH_S + idx];
    float nt = sqrtf(fmaxf(hhk[k] - 2.f*rhtk[k] + rrt, 0.f));
    float ns = sqrtf(fmaxf(hhk[k] - 2.f*rhsk[k] + rrs, 0.f));
    ihr_t[k] = 1.f / fmaxf(nt, 1e-8f);
    ihr_s[k] = 1.f / fmaxf(ns, 1e-8f);
  }

  float local = 0.f;
#pragma unroll
  for (int h = 0; h < 4; ++h) {
    // dump s16-quarter h into per-wave slab (same-wave LDS ordering)
#pragma unroll
    for (int q2 = 0; q2 < 4; ++q2) {
      int rg = lq*4 + q2;
      Ct[w][ 0 + rg][l15] = aT0[h][q2];
      Ct[w][16 + rg][l15] = aT1[h][q2];
      Ct[w][32 + rg][l15] = aT2[h][q2];
      Ct[w][48 + rg][l15] = aT3[h][q2];
      Ct[w][64 + rg][l15] = aRT[h][q2];
      Cs2[w][ 0 + rg][l15] = aS0[h][q2];
      Cs2[w][16 + rg][l15] = aS1[h][q2];
      Cs2[w][32 + rg][l15] = aS2[h][q2];
      Cs2[w][48 + rg][l15] = aS3[h][q2];
      Cs2[w][64 + rg][l15] = aRS[h][q2];
    }
#pragma unroll
    for (int j = 0; j < 4; ++j) {
      int sl = sg*4 + j;
      int sidx = z*SSZ + s0 + h*16 + sl;
      float sst = ws[OFF_SS_T + sidx];
      float sss = ws[OFF_SS_S + sidx];
      float srt = Ct[w][64 + rl][sl];
      float srs = Cs2[w][64 + rl][sl];
      float isr_t = 1.f / fmaxf(sqrtf(fmaxf(sst - 2.f*srt + rrt, 0.f)), 1e-8f);
      float isr_s = 1.f / fmaxf(sqrtf(fmaxf(sss - 2.f*srs + rrs, 0.f)), 1e-8f);
#pragma unroll
      for (int k = 0; k < 4; ++k) {
        float sht = Ct[w][rl*4 + k][sl];
        float shs = Cs2[w][rl*4 + k][sl];
        float ish_t = 1.f / fmaxf(sqrtf(fmaxf(sst - 2.f*sht + hhk[k], 0.f)), 1e-8f);
        float ish_s = 1.f / fmaxf(sqrtf(fmaxf(sss - 2.f*shs + hhk[k], 0.f)), 1e-8f);
        float a1t = (sht - rhtk[k] - srt + rrt) * (isr_t * ihr_t[k]);
        float a2t = (srt - sht - rhtk[k] + hhk[k]) * (ihr_t[k] * ish_t);
        float a3t = (rhtk[k] - srt - sht + sst) * (isr_t * ish_t);
        float a1s = (shs - rhsk[k] - srs + rrs) * (isr_s * ihr_s[k]);
        float a2s = (srs - shs - rhsk[k] + hhk[k]) * (ihr_s[k] * ish_s);
        float a3s = (rhsk[k] - srs - shs + sss) * (isr_s * ish_s);
        local += fabsf(a1s - a1t) + fabsf(a2s - a2t) + fabsf(a3s - a3t);
      }
    }
  }

  // block sum over 192 threads (3 waves)
  float v = local;
  v += __shfl_down(v, 32); v += __shfl_down(v, 16);
  v += __shfl_down(v, 8);  v += __shfl_down(v, 4);
  v += __shfl_down(v, 2);  v += __shfl_down(v, 1);
  if (lane == 0) sb[w] = v;
  __syncthreads();
  if (tid == 0) {
    atomicAdd(acc_out, (double)(sb[0] + sb[1] + sb[2]));
    __threadfence();
    int* cnt = (int*)(acc_out + 1);
    int prev = atomicAdd(cnt, 1);
    if (prev == 255) {                 // last block: finalize
      __threadfence();
      double total = atomicAdd(acc_out, 0.0);
      out[0] = (float)(total / 3145728.0);   // 3 * B * R * S * K
    }
  }
}

extern "C" void kernel_launch(void* const* d_in, const int* in_sizes, int n_in,
                              void* d_out, int out_size, void* d_ws, size_t ws_size,
                              hipStream_t stream) {
  const float* T  = (const float*)d_in[0];
  const float* Sf = (const float*)d_in[1];
  const int* ref_perm    = (const int*)d_in[2];
  const int* shared_perm = (const int*)d_in[3];
  float* ws = (float*)d_ws;
  double* acc = (double*)(ws + OFF_ACC);

  hipMemsetAsync(acc, 0, 16, stream);   // acc double + completion counter
  k_prep<<<20480, 256, 0, stream>>>(T, Sf, ref_perm, shared_perm, ws);
  k_sim<<<1024, 256, 0, stream>>>(ws);
  k_select<<<BB*RR, 256, 0, stream>>>(T, Sf, ref_perm, ws);
  k_main<<<256, 192, 0, stream>>>(ws, acc, (float*)d_out);
}

// Round 24
// 121.498 us; speedup vs baseline: 1.1560x; 1.1560x over previous
//
#include <hip/hip_runtime.h>
#include <float.h>

#define BB 4
#define PP 1024
#define DD 1024
#define RR 256
#define SSZ 256
#define KT 4
#define EE 4096
#define NPAIR 3

typedef float  f32x4  __attribute__((ext_vector_type(4)));
typedef short  short8 __attribute__((ext_vector_type(8)));

#define MFMA16(a,b,c) __builtin_amdgcn_mfma_f32_16x16x32_bf16((a),(b),(c),0,0,0)

// ---- float-region offsets (in floats) ----
#define OFF_NE    ((size_t)0)         // BB*EE
#define OFF_RR_T  ((size_t)16384)     // BB*RR
#define OFF_RR_S  ((size_t)17408)
#define OFF_HH    ((size_t)18432)     // BB*RR*KT
#define OFF_RH_T  ((size_t)22528)
#define OFF_RH_S  ((size_t)26624)
#define OFF_SS_T  ((size_t)30720)     // NPAIR*BB*SSZ
#define OFF_SS_S  ((size_t)33792)
#define OFF_TOPK  ((size_t)36864)     // BB*RR*KT ints
#define OFF_ACC   ((size_t)40960)     // double + int counter (16 B zeroed)
#define OFF_CAND  ((size_t)45056)     // BB*RR*64*4 float2 = 524288 floats
#define FLOAT_END ((size_t)569344)

// ---- ushort (bf16 hi) regions, K-major 16-row-group layout ----
// group g: [32 k-chunks][16 rows][4 swizzled 16B slots]
//   elem (row R, k): g=R>>4, rr=R&15, c=k>>5, s=(k>>3)&3, slot=s^((rr>>1)&3)
//   ushort off = base + g*16384 + c*512 + rr*32 + slot*8 + (k&7)
#define U_REF_T ((size_t)0)           // BB*RR*DD
#define U_REF_S ((size_t)2097152)
#define U_SIMH  ((size_t)4194304)     // BB*RR*KT*DD
#define U_SH_T  ((size_t)8388608)     // NPAIR*BB*SSZ*DD
#define U_SH_S  ((size_t)11534336)
#define U_EXT   ((size_t)14680064)    // BB*EE*DD
// end 31457280 ushorts; total ws ~65.2 MB

__device__ inline float block_sum256(float v, float* sb) {
  v += __shfl_down(v, 32); v += __shfl_down(v, 16);
  v += __shfl_down(v, 8);  v += __shfl_down(v, 4);
  v += __shfl_down(v, 2);  v += __shfl_down(v, 1);
  int lane = threadIdx.x & 63, wid = threadIdx.x >> 6;
  if (lane == 0) sb[wid] = v;
  __syncthreads();
  float r = 0.f;
  if (threadIdx.x < 4) r = sb[threadIdx.x];
  r += __shfl_down(r, 2); r += __shfl_down(r, 1);
  __syncthreads();
  return r;   // valid on thread 0
}

__device__ inline float dot4(const float4& a, const float4& b) {
  return a.x*b.x + a.y*b.y + a.z*b.z + a.w*b.w;
}

// round-to-nearest-even bf16
__device__ inline unsigned short bhi(float x) {
  unsigned u = __float_as_uint(x);
  return (unsigned short)((u + 0x7fffu + ((u >> 16) & 1u)) >> 16);
}
__device__ inline ushort4 h4of(float4 f) {
  return make_ushort4(bhi(f.x), bhi(f.y), bhi(f.z), bhi(f.w));
}

// writer offset for thread t (t=0..255, k=4t..4t+3) of global row R
__device__ inline size_t wofs(size_t base, int R, int t) {
  int rr = R & 15;
  int ss = ((t >> 1) & 3) ^ ((rr >> 1) & 3);
  return base + (size_t)(R >> 4)*16384 + (size_t)(t >> 3)*512
       + rr*32 + ss*8 + (t & 1)*4;
}

// ---- fused prep: gather_ref (0..1023) | ne (1024..17407) | ss (17408..20479) ----
__global__ __launch_bounds__(256) void k_prep(const float* __restrict__ T,
                                              const float* __restrict__ Sf,
                                              const int* __restrict__ ref_perm,
                                              const int* __restrict__ shared_perm,
                                              float* __restrict__ ws) {
  __shared__ float sb[4];
  ushort* uws = (ushort*)(ws + FLOAT_END);
  int blk = blockIdx.x;
  int t = threadIdx.x;
  if (blk < 1024) {
    int b = blk >> 8, r = blk & 255;
    int pos = ref_perm[r];
    const float4* ts = (const float4*)(T  + ((size_t)(b*8 + 0)*PP + pos)*DD);
    const float4* sv = (const float4*)(Sf + ((size_t)(b*4 + 0)*PP + pos)*DD);
    float4 a = ts[t], c = sv[t];
    int R = b*RR + r;
    *(ushort4*)(uws + wofs(U_REF_T, R, t)) = h4of(a);
    *(ushort4*)(uws + wofs(U_REF_S, R, t)) = h4of(c);
    float r1 = block_sum256(dot4(a, a), sb);
    float r2 = block_sum256(dot4(c, c), sb);
    if (t == 0) {
      ws[OFF_RR_T + R] = r1;
      ws[OFF_RR_S + R] = r2;
    }
  } else if (blk < 17408) {
    int i = blk - 1024;
    int b = i >> 12, e = i & 4095;
    int f = 1 + 2*(e >> 10);
    int pos = e & 1023;
    const float4* src = (const float4*)(T + ((size_t)(b*8 + f)*PP + pos)*DD);
    float4 a = src[t];
    *(ushort4*)(uws + wofs(U_EXT, b*EE + e, t)) = h4of(a);
    float tot = block_sum256(dot4(a, a), sb);
    if (t == 0) ws[OFF_NE + (size_t)b*EE + e] = fmaxf(sqrtf(tot), 1e-12f);
  } else {
    int idx = blk - 17408;                 // z*SSZ + s
    int p = idx / (BB*SSZ);
    int b = (idx / SSZ) % BB;
    int s = idx % SSZ;
    int pos = shared_perm[s];
    int ti = 2*(p + 1), si = p + 1;
    const float4* tr = (const float4*)(T  + ((size_t)(b*8 + ti)*PP + pos)*DD);
    const float4* sr = (const float4*)(Sf + ((size_t)(b*4 + si)*PP + pos)*DD);
    float4 a = tr[t], c = sr[t];
    *(ushort4*)(uws + wofs(U_SH_T, idx, t)) = h4of(a);
    *(ushort4*)(uws + wofs(U_SH_S, idx, t)) = h4of(c);
    float r1 = block_sum256(dot4(a, a), sb);
    float r2 = block_sum256(dot4(c, c), sb);
    if (t == 0) { ws[OFF_SS_T + idx] = r1; ws[OFF_SS_S + idx] = r2; }
  }
}

// ---- sim GEMM: BARRIER-FREE. One wave per (r16, e64) tile. ----
__global__ __launch_bounds__(256) void k_sim(float* __restrict__ ws) {
  __shared__ float simv[4][16][68];
  const ushort* uws = (const ushort*)(ws + FLOAT_END);
  int d = blockIdx.x;
  int u8 = d & 7, q = d >> 3;          // q 0..127
  int b = u8 >> 1, eh = u8 & 1;
  int eb = eh*32 + (q >> 2);           // e64-block 0..63
  int rgq = q & 3;
  int tid = threadIdx.x;
  int w = tid >> 6, lane = tid & 63;
  int rg = rgq*4 + w;                  // r16-group 0..15
  int r0 = rg*16, e0 = eb*64;
  int l15 = lane & 15, lq = (lane >> 4) & 3;
  int laneoff = l15*32 + ((lq ^ ((l15 >> 1) & 3)))*8;

  const ushort* pA = uws + U_REF_T + ((size_t)((b*RR + r0) >> 4))*16384 + laneoff;
  const ushort* pB0 = uws + U_EXT + ((size_t)((b*EE + e0) >> 4) + 0)*16384 + laneoff;
  const ushort* pB1 = uws + U_EXT + ((size_t)((b*EE + e0) >> 4) + 1)*16384 + laneoff;
  const ushort* pB2 = uws + U_EXT + ((size_t)((b*EE + e0) >> 4) + 2)*16384 + laneoff;
  const ushort* pB3 = uws + U_EXT + ((size_t)((b*EE + e0) >> 4) + 3)*16384 + laneoff;

  f32x4 acc[4];
#pragma unroll
  for (int j = 0; j < 4; ++j) acc[j] = (f32x4){0.f, 0.f, 0.f, 0.f};

#pragma unroll 4
  for (int c = 0; c < 32; ++c) {
    int o = c*512;
    short8 ah = *(const short8*)(pA + o);
    short8 b0 = *(const short8*)(pB0 + o);
    short8 b1 = *(const short8*)(pB1 + o);
    short8 b2 = *(const short8*)(pB2 + o);
    short8 b3 = *(const short8*)(pB3 + o);
    acc[0] = MFMA16(ah, b0, acc[0]);
    acc[1] = MFMA16(ah, b1, acc[1]);
    acc[2] = MFMA16(ah, b2, acc[2]);
    acc[3] = MFMA16(ah, b3, acc[3]);
  }

  float invs[4];
#pragma unroll
  for (int j = 0; j < 4; ++j)
    invs[j] = 1.f / ws[OFF_NE + (size_t)b*EE + e0 + j*16 + l15];
#pragma unroll
  for (int j = 0; j < 4; ++j)
#pragma unroll
    for (int q2 = 0; q2 < 4; ++q2)
      simv[w][lq*4 + q2][j*16 + l15] = acc[j][q2] * invs[j];
  // same-wave LDS write->read: lgkmcnt ordering only, no barrier needed
  if (lane < 16) {
    float v[4] = {-FLT_MAX, -FLT_MAX, -FLT_MAX, -FLT_MAX};
    int ix[4] = {0x7fffffff, 0x7fffffff, 0x7fffffff, 0x7fffffff};
#pragma unroll 1
    for (int e = 0; e < 64; ++e) {
      float f = simv[w][lane][e];
      if (f > v[3]) {
        int eg = e0 + e;
        if (f > v[0])      { v[3]=v[2]; ix[3]=ix[2]; v[2]=v[1]; ix[2]=ix[1]; v[1]=v[0]; ix[1]=ix[0]; v[0]=f; ix[0]=eg; }
        else if (f > v[1]) { v[3]=v[2]; ix[3]=ix[2]; v[2]=v[1]; ix[2]=ix[1]; v[1]=f; ix[1]=eg; }
        else if (f > v[2]) { v[3]=v[2]; ix[3]=ix[2]; v[2]=f; ix[2]=eg; }
        else               { v[3]=f; ix[3]=eg; }
      }
    }
    float2* cand = (float2*)(ws + OFF_CAND);
    size_t base = (((size_t)(b*RR + r0 + lane))*64 + eb)*4;
#pragma unroll
    for (int k = 0; k < 4; ++k)
      cand[base + k] = make_float2(v[k], __int_as_float(ix[k]));
  }
}

// ---- merged select: top-4 merge + gather + hh/rh dots, one block per (b,r) ----
__global__ __launch_bounds__(256) void k_select(const float* __restrict__ T,
                                                const float* __restrict__ Sf,
                                                const int* __restrict__ ref_perm,
                                                float* __restrict__ ws) {
  __shared__ float rv[256];
  __shared__ int   ri[256];
  __shared__ int   winIdx;
  __shared__ int   sel[4];
  int br = blockIdx.x;
  int tid = threadIdx.x;
  const float2* cand = (const float2*)(ws + OFF_CAND);
  float2 c0 = cand[(size_t)br*256 + tid];
  float v = c0.x;
  int idx = __float_as_int(c0.y);
  int* outi = (int*)(ws + OFF_TOPK) + (size_t)br*KT;
  for (int k = 0; k < KT; ++k) {
    rv[tid] = v; ri[tid] = idx;
    __syncthreads();
    for (int off = 128; off > 0; off >>= 1) {
      if (tid < off) {
        float v2 = rv[tid+off]; int i2 = ri[tid+off];
        if (v2 > rv[tid] || (v2 == rv[tid] && i2 < ri[tid])) { rv[tid] = v2; ri[tid] = i2; }
      }
      __syncthreads();
    }
    if (tid == 0) { outi[k] = ri[0]; winIdx = ri[0]; sel[k] = ri[0]; }
    __syncthreads();
    if (idx == winIdx) v = -FLT_MAX;
    __syncthreads();
  }

  // phase 2: gather 4 selected rows (group g = k), bf16 store + 3 dots each
  int b = br >> 8, r = br & 255;
  int g = tid >> 6, lane = tid & 63;
  int e = sel[g];
  int rpos = ref_perm[r];
  const float4* src = (const float4*)(T + ((size_t)(b*8 + 1 + 2*(e >> 10))*PP + (e & 1023))*DD);
  const float4* rt  = (const float4*)(T  + ((size_t)(b*8 + 0)*PP + rpos)*DD);
  const float4* rs  = (const float4*)(Sf + ((size_t)(b*4 + 0)*PP + rpos)*DD);
  ushort* uws = (ushort*)(ws + FLOAT_END);
  int rowi = br*KT + g;
  float hh = 0.f, rht = 0.f, rhs = 0.f;
#pragma unroll
  for (int i = 0; i < 4; ++i) {
    int t4 = lane*4 + i;               // 0..255
    float4 h = src[t4];
    *(ushort4*)(uws + wofs(U_SIMH, rowi, t4)) = h4of(h);
    float4 a = rt[t4], c = rs[t4];
    hh  += dot4(h, h);
    rht += dot4(h, a);
    rhs += dot4(h, c);
  }
  hh  += __shfl_down(hh, 32);  hh  += __shfl_down(hh, 16);
  hh  += __shfl_down(hh, 8);   hh  += __shfl_down(hh, 4);
  hh  += __shfl_down(hh, 2);   hh  += __shfl_down(hh, 1);
  rht += __shfl_down(rht, 32); rht += __shfl_down(rht, 16);
  rht += __shfl_down(rht, 8);  rht += __shfl_down(rht, 4);
  rht += __shfl_down(rht, 2);  rht += __shfl_down(rht, 1);
  rhs += __shfl_down(rhs, 32); rhs += __shfl_down(rhs, 16);
  rhs += __shfl_down(rhs, 8);  rhs += __shfl_down(rhs, 4);
  rhs += __shfl_down(rhs, 2);  rhs += __shfl_down(rhs, 1);
  if (lane == 0) {
    ws[OFF_HH + rowi]   = hh;
    ws[OFF_RH_T + rowi] = rht;
    ws[OFF_RH_S + rowi] = rhs;
  }
}

// ---- main fused kernel: BARRIER-FREE, s32 per wave, balanced 512x192 ----
// 1536 wave-tiles; 3 waves/block, 512 blocks = exactly 2 blocks/CU.
// u8 = d&7 (XCD pin); t = (d>>3)*3 + w in [0,192): p = t>>6; s32i = (t&63)>>3;
// r16q = t&7; r16i = rhalf*8 + r16q.  k_final fused via completion counter.
__global__ __launch_bounds__(192) void k_main(float* __restrict__ ws,
                                              double* __restrict__ acc_out,
                                              float* __restrict__ out) {
  __shared__ float Ct[3][80][17];
  __shared__ float Cs2[3][80][17];
  __shared__ float sb[3];
  const ushort* uws = (const ushort*)(ws + FLOAT_END);

  int d = blockIdx.x;
  int u8 = d & 7, q = d >> 3;        // q 0..63
  int b = u8 >> 1, rhalf = u8 & 1;
  int tid = threadIdx.x;
  int w = tid >> 6, lane = tid & 63;
  int t = q*3 + w;                   // 0..191
  int p = t >> 6;
  int rem = t & 63;
  int s32i = rem >> 3, r16q = rem & 7;
  int z = p*4 + b;
  int r16i = rhalf*8 + r16q;
  int r0 = r16i*16, s0 = s32i*32;

  int l15 = lane & 15, lq = (lane >> 4) & 3;
  int laneoff = l15*32 + ((lq ^ ((l15 >> 1) & 3)))*8;

  // fragment pointers (each contiguous 1 KB per k-step)
  const ushort* pa0; const ushort* pa1; const ushort* pa2; const ushort* pa3;
  const ushort* prt; const ushort* prs;
  const ushort* pbt0; const ushort* pbt1; const ushort* pbs0; const ushort* pbs1;
  {
    size_t gs = (size_t)((b*RR + r0) >> 2);      // simh group base (4 groups)
    pa0 = uws + U_SIMH + (gs + 0)*16384 + laneoff;
    pa1 = uws + U_SIMH + (gs + 1)*16384 + laneoff;
    pa2 = uws + U_SIMH + (gs + 2)*16384 + laneoff;
    pa3 = uws + U_SIMH + (gs + 3)*16384 + laneoff;
    size_t gr = (size_t)((b*RR + r0) >> 4);
    prt = uws + U_REF_T + gr*16384 + laneoff;
    prs = uws + U_REF_S + gr*16384 + laneoff;
    size_t gh = (size_t)((z*SSZ + s0) >> 4);
    pbt0 = uws + U_SH_T + (gh + 0)*16384 + laneoff;
    pbt1 = uws + U_SH_T + (gh + 1)*16384 + laneoff;
    pbs0 = uws + U_SH_S + (gh + 0)*16384 + laneoff;
    pbs1 = uws + U_SH_S + (gh + 1)*16384 + laneoff;
  }

  f32x4 aT0[2], aT1[2], aT2[2], aT3[2], aRT[2];
  f32x4 aS0[2], aS1[2], aS2[2], aS3[2], aRS[2];
#pragma unroll
  for (int h = 0; h < 2; ++h) {
    aT0[h] = aT1[h] = aT2[h] = aT3[h] = aRT[h] = (f32x4){0.f,0.f,0.f,0.f};
    aS0[h] = aS1[h] = aS2[h] = aS3[h] = aRS[h] = (f32x4){0.f,0.f,0.f,0.f};
  }

#pragma unroll 2
  for (int c = 0; c < 32; ++c) {
    int o = c*512;
    short8 bt0 = *(const short8*)(pbt0 + o);
    short8 bt1 = *(const short8*)(pbt1 + o);
    short8 bs0 = *(const short8*)(pbs0 + o);
    short8 bs1 = *(const short8*)(pbs1 + o);
    short8 a0 = *(const short8*)(pa0 + o);
    short8 a1 = *(const short8*)(pa1 + o);
    short8 a2 = *(const short8*)(pa2 + o);
    short8 a3 = *(const short8*)(pa3 + o);
    short8 rt = *(const short8*)(prt + o);
    short8 rs = *(const short8*)(prs + o);
    aT0[0] = MFMA16(a0, bt0, aT0[0]);  aT0[1] = MFMA16(a0, bt1, aT0[1]);
    aT1[0] = MFMA16(a1, bt0, aT1[0]);  aT1[1] = MFMA16(a1, bt1, aT1[1]);
    aT2[0] = MFMA16(a2, bt0, aT2[0]);  aT2[1] = MFMA16(a2, bt1, aT2[1]);
    aT3[0] = MFMA16(a3, bt0, aT3[0]);  aT3[1] = MFMA16(a3, bt1, aT3[1]);
    aRT[0] = MFMA16(rt, bt0, aRT[0]);  aRT[1] = MFMA16(rt, bt1, aRT[1]);
    aS0[0] = MFMA16(a0, bs0, aS0[0]);  aS0[1] = MFMA16(a0, bs1, aS0[1]);
    aS1[0] = MFMA16(a1, bs0, aS1[0]);  aS1[1] = MFMA16(a1, bs1, aS1[1]);
    aS2[0] = MFMA16(a2, bs0, aS2[0]);  aS2[1] = MFMA16(a2, bs1, aS2[1]);
    aS3[0] = MFMA16(a3, bs0, aS3[0]);  aS3[1] = MFMA16(a3, bs1, aS3[1]);
    aRS[0] = MFMA16(rs, bs0, aRS[0]);  aRS[1] = MFMA16(rs, bs1, aRS[1]);
  }

  // per-r scalars (h-independent)
  int rl = lane >> 2, sg = lane & 3;
  int r = r0 + rl;
  float rrt = ws[OFF_RR_T + b*RR + r];
  float rrs = ws[OFF_RR_S + b*RR + r];
  float hhk[4], rhtk[4], rhsk[4], ihr_t[4], ihr_s[4];
#pragma unroll
  for (int k = 0; k < 4; ++k) {
    int idx = (b*RR + r)*KT + k;
    hhk[k]  = ws[OFF_HH + idx];
    rhtk[k] = ws[OFF_RH_T + idx];
    rhsk[k] = ws[OFF_RH_S + idx];
    float nt = sqrtf(fmaxf(hhk[k] - 2.f*rhtk[k] + rrt, 0.f));
    float ns = sqrtf(fmaxf(hhk[k] - 2.f*rhsk[k] + rrs, 0.f));
    ihr_t[k] = 1.f / fmaxf(nt, 1e-8f);
    ihr_s[k] = 1.f / fmaxf(ns, 1e-8f);
  }

  float local = 0.f;
#pragma unroll
  for (int h = 0; h < 2; ++h) {
    // dump half h into per-wave slab (same-wave LDS ordering, no barrier)
#pragma unroll
    for (int q2 = 0; q2 < 4; ++q2) {
      int rg = lq*4 + q2;
      Ct[w][ 0 + rg][l15] = aT0[h][q2];
      Ct[w][16 + rg][l15] = aT1[h][q2];
      Ct[w][32 + rg][l15] = aT2[h][q2];
      Ct[w][48 + rg][l15] = aT3[h][q2];
      Ct[w][64 + rg][l15] = aRT[h][q2];
      Cs2[w][ 0 + rg][l15] = aS0[h][q2];
      Cs2[w][16 + rg][l15] = aS1[h][q2];
      Cs2[w][32 + rg][l15] = aS2[h][q2];
      Cs2[w][48 + rg][l15] = aS3[h][q2];
      Cs2[w][64 + rg][l15] = aRS[h][q2];
    }
#pragma unroll
    for (int j = 0; j < 4; ++j) {
      int sl = sg*4 + j;
      int sidx = z*SSZ + s0 + h*16 + sl;
      float sst = ws[OFF_SS_T + sidx];
      float sss = ws[OFF_SS_S + sidx];
      float srt = Ct[w][64 + rl][sl];
      float srs = Cs2[w][64 + rl][sl];
      float isr_t = 1.f / fmaxf(sqrtf(fmaxf(sst - 2.f*srt + rrt, 0.f)), 1e-8f);
      float isr_s = 1.f / fmaxf(sqrtf(fmaxf(sss - 2.f*srs + rrs, 0.f)), 1e-8f);
#pragma unroll
      for (int k = 0; k < 4; ++k) {
        float sht = Ct[w][rl*4 + k][sl];
        float shs = Cs2[w][rl*4 + k][sl];
        float ish_t = 1.f / fmaxf(sqrtf(fmaxf(sst - 2.f*sht + hhk[k], 0.f)), 1e-8f);
        float ish_s = 1.f / fmaxf(sqrtf(fmaxf(sss - 2.f*shs + hhk[k], 0.f)), 1e-8f);
        float a1t = (sht - rhtk[k] - srt + rrt) * (isr_t * ihr_t[k]);
        float a2t = (srt - sht - rhtk[k] + hhk[k]) * (ihr_t[k] * ish_t);
        float a3t = (rhtk[k] - srt - sht + sst) * (isr_t * ish_t);
        float a1s = (shs - rhsk[k] - srs + rrs) * (isr_s * ihr_s[k]);
        float a2s = (srs - shs - rhsk[k] + hhk[k]) * (ihr_s[k] * ish_s);
        float a3s = (rhsk[k] - srs - shs + sss) * (isr_s * ish_s);
        local += fabsf(a1s - a1t) + fabsf(a2s - a2t) + fabsf(a3s - a3t);
      }
    }
  }

  // block sum over 192 threads (3 waves)
  float v = local;
  v += __shfl_down(v, 32); v += __shfl_down(v, 16);
  v += __shfl_down(v, 8);  v += __shfl_down(v, 4);
  v += __shfl_down(v, 2);  v += __shfl_down(v, 1);
  if (lane == 0) sb[w] = v;
  __syncthreads();
  if (tid == 0) {
    atomicAdd(acc_out, (double)(sb[0] + sb[1] + sb[2]));
    __threadfence();
    int* cnt = (int*)(acc_out + 1);
    int prev = atomicAdd(cnt, 1);
    if (prev == 511) {                 // last of 512 blocks: finalize
      __threadfence();
      double total = atomicAdd(acc_out, 0.0);
      out[0] = (float)(total / 3145728.0);   // 3 * B * R * S * K
    }
  }
}

extern "C" void kernel_launch(void* const* d_in, const int* in_sizes, int n_in,
                              void* d_out, int out_size, void* d_ws, size_t ws_size,
                              hipStream_t stream) {
  const float* T  = (const float*)d_in[0];
  const float* Sf = (const float*)d_in[1];
  const int* ref_perm    = (const int*)d_in[2];
  const int* shared_perm = (const int*)d_in[3];
  float* ws = (float*)d_ws;
  double* acc = (double*)(ws + OFF_ACC);

  hipMemsetAsync(acc, 0, 16, stream);   // acc double + completion counter
  k_prep<<<20480, 256, 0, stream>>>(T, Sf, ref_perm, shared_perm, ws);
  k_sim<<<1024, 256, 0, stream>>>(ws);
  k_select<<<BB*RR, 256, 0, stream>>>(T, Sf, ref_perm, ws);
  k_main<<<512, 192, 0, stream>>>(ws, acc, (float*)d_out);
}

// Round 25
// 117.938 us; speedup vs baseline: 1.1909x; 1.0302x over previous
//
#include <hip/hip_runtime.h>
#include <float.h>

#define BB 4
#define PP 1024
#define DD 1024
#define RR 256
#define SSZ 256
#define KT 4
#define EE 4096
#define NPAIR 3

typedef float  f32x4  __attribute__((ext_vector_type(4)));
typedef short  short8 __attribute__((ext_vector_type(8)));

#define MFMA16(a,b,c) __builtin_amdgcn_mfma_f32_16x16x32_bf16((a),(b),(c),0,0,0)

// ---- float-region offsets (in floats) ----
#define OFF_NE    ((size_t)0)         // BB*EE
#define OFF_RR_T  ((size_t)16384)     // BB*RR
#define OFF_RR_S  ((size_t)17408)
#define OFF_HH    ((size_t)18432)     // BB*RR*KT
#define OFF_RH_T  ((size_t)22528)
#define OFF_RH_S  ((size_t)26624)
#define OFF_SS_T  ((size_t)30720)     // NPAIR*BB*SSZ
#define OFF_SS_S  ((size_t)33792)
#define OFF_TOPK  ((size_t)36864)     // BB*RR*KT ints
#define OFF_ACC   ((size_t)40960)     // double
#define OFF_CAND  ((size_t)45056)     // BB*RR*64*4 float2 = 524288 floats
#define FLOAT_END ((size_t)569344)

// ---- ushort (bf16 hi) regions, K-major 16-row-group layout ----
// group g: [32 k-chunks][16 rows][4 swizzled 16B slots]
//   elem (row R, k): g=R>>4, rr=R&15, c=k>>5, s=(k>>3)&3, slot=s^((rr>>1)&3)
//   ushort off = base + g*16384 + c*512 + rr*32 + slot*8 + (k&7)
#define U_REF_T ((size_t)0)           // BB*RR*DD
#define U_REF_S ((size_t)2097152)
#define U_SIMH  ((size_t)4194304)     // BB*RR*KT*DD
#define U_SH_T  ((size_t)8388608)     // NPAIR*BB*SSZ*DD
#define U_SH_S  ((size_t)11534336)
#define U_EXT   ((size_t)14680064)    // BB*EE*DD
// end 31457280 ushorts; total ws ~65.2 MB

__device__ inline float block_sum256(float v, float* sb) {
  v += __shfl_down(v, 32); v += __shfl_down(v, 16);
  v += __shfl_down(v, 8);  v += __shfl_down(v, 4);
  v += __shfl_down(v, 2);  v += __shfl_down(v, 1);
  int lane = threadIdx.x & 63, wid = threadIdx.x >> 6;
  if (lane == 0) sb[wid] = v;
  __syncthreads();
  float r = 0.f;
  if (threadIdx.x < 4) r = sb[threadIdx.x];
  r += __shfl_down(r, 2); r += __shfl_down(r, 1);
  __syncthreads();
  return r;   // valid on thread 0
}

__device__ inline float dot4(const float4& a, const float4& b) {
  return a.x*b.x + a.y*b.y + a.z*b.z + a.w*b.w;
}

// round-to-nearest-even bf16
__device__ inline unsigned short bhi(float x) {
  unsigned u = __float_as_uint(x);
  return (unsigned short)((u + 0x7fffu + ((u >> 16) & 1u)) >> 16);
}
__device__ inline ushort4 h4of(float4 f) {
  return make_ushort4(bhi(f.x), bhi(f.y), bhi(f.z), bhi(f.w));
}

// writer offset for thread t (t=0..255, k=4t..4t+3) of global row R
__device__ inline size_t wofs(size_t base, int R, int t) {
  int rr = R & 15;
  int ss = ((t >> 1) & 3) ^ ((rr >> 1) & 3);
  return base + (size_t)(R >> 4)*16384 + (size_t)(t >> 3)*512
       + rr*32 + ss*8 + (t & 1)*4;
}

// ---- fused prep: gather_ref (0..1023) | ne (1024..17407) | ss (17408..20479) ----
__global__ __launch_bounds__(256) void k_prep(const float* __restrict__ T,
                                              const float* __restrict__ Sf,
                                              const int* __restrict__ ref_perm,
                                              const int* __restrict__ shared_perm,
                                              float* __restrict__ ws) {
  __shared__ float sb[4];
  ushort* uws = (ushort*)(ws + FLOAT_END);
  int blk = blockIdx.x;
  int t = threadIdx.x;
  if (blk < 1024) {
    int b = blk >> 8, r = blk & 255;
    int pos = ref_perm[r];
    const float4* ts = (const float4*)(T  + ((size_t)(b*8 + 0)*PP + pos)*DD);
    const float4* sv = (const float4*)(Sf + ((size_t)(b*4 + 0)*PP + pos)*DD);
    float4 a = ts[t], c = sv[t];
    int R = b*RR + r;
    *(ushort4*)(uws + wofs(U_REF_T, R, t)) = h4of(a);
    *(ushort4*)(uws + wofs(U_REF_S, R, t)) = h4of(c);
    float r1 = block_sum256(dot4(a, a), sb);
    float r2 = block_sum256(dot4(c, c), sb);
    if (t == 0) {
      ws[OFF_RR_T + R] = r1;
      ws[OFF_RR_S + R] = r2;
    }
  } else if (blk < 17408) {
    int i = blk - 1024;
    int b = i >> 12, e = i & 4095;
    int f = 1 + 2*(e >> 10);
    int pos = e & 1023;
    const float4* src = (const float4*)(T + ((size_t)(b*8 + f)*PP + pos)*DD);
    float4 a = src[t];
    *(ushort4*)(uws + wofs(U_EXT, b*EE + e, t)) = h4of(a);
    float tot = block_sum256(dot4(a, a), sb);
    if (t == 0) ws[OFF_NE + (size_t)b*EE + e] = fmaxf(sqrtf(tot), 1e-12f);
  } else {
    int idx = blk - 17408;                 // z*SSZ + s
    int p = idx / (BB*SSZ);
    int b = (idx / SSZ) % BB;
    int s = idx % SSZ;
    int pos = shared_perm[s];
    int ti = 2*(p + 1), si = p + 1;
    const float4* tr = (const float4*)(T  + ((size_t)(b*8 + ti)*PP + pos)*DD);
    const float4* sr = (const float4*)(Sf + ((size_t)(b*4 + si)*PP + pos)*DD);
    float4 a = tr[t], c = sr[t];
    *(ushort4*)(uws + wofs(U_SH_T, idx, t)) = h4of(a);
    *(ushort4*)(uws + wofs(U_SH_S, idx, t)) = h4of(c);
    float r1 = block_sum256(dot4(a, a), sb);
    float r2 = block_sum256(dot4(c, c), sb);
    if (t == 0) { ws[OFF_SS_T + idx] = r1; ws[OFF_SS_S + idx] = r2; }
  }
}

// ---- sim GEMM: BARRIER-FREE. One wave per (r16, e64) tile. ----
__global__ __launch_bounds__(256) void k_sim(float* __restrict__ ws) {
  __shared__ float simv[4][16][68];
  const ushort* uws = (const ushort*)(ws + FLOAT_END);
  int d = blockIdx.x;
  int u8 = d & 7, q = d >> 3;          // q 0..127
  int b = u8 >> 1, eh = u8 & 1;
  int eb = eh*32 + (q >> 2);           // e64-block 0..63
  int rgq = q & 3;
  int tid = threadIdx.x;
  int w = tid >> 6, lane = tid & 63;
  int rg = rgq*4 + w;                  // r16-group 0..15
  int r0 = rg*16, e0 = eb*64;
  int l15 = lane & 15, lq = (lane >> 4) & 3;
  int laneoff = l15*32 + ((lq ^ ((l15 >> 1) & 3)))*8;

  const ushort* pA = uws + U_REF_T + ((size_t)((b*RR + r0) >> 4))*16384 + laneoff;
  const ushort* pB0 = uws + U_EXT + ((size_t)((b*EE + e0) >> 4) + 0)*16384 + laneoff;
  const ushort* pB1 = uws + U_EXT + ((size_t)((b*EE + e0) >> 4) + 1)*16384 + laneoff;
  const ushort* pB2 = uws + U_EXT + ((size_t)((b*EE + e0) >> 4) + 2)*16384 + laneoff;
  const ushort* pB3 = uws + U_EXT + ((size_t)((b*EE + e0) >> 4) + 3)*16384 + laneoff;

  f32x4 acc[4];
#pragma unroll
  for (int j = 0; j < 4; ++j) acc[j] = (f32x4){0.f, 0.f, 0.f, 0.f};

#pragma unroll 4
  for (int c = 0; c < 32; ++c) {
    int o = c*512;
    short8 ah = *(const short8*)(pA + o);
    short8 b0 = *(const short8*)(pB0 + o);
    short8 b1 = *(const short8*)(pB1 + o);
    short8 b2 = *(const short8*)(pB2 + o);
    short8 b3 = *(const short8*)(pB3 + o);
    acc[0] = MFMA16(ah, b0, acc[0]);
    acc[1] = MFMA16(ah, b1, acc[1]);
    acc[2] = MFMA16(ah, b2, acc[2]);
    acc[3] = MFMA16(ah, b3, acc[3]);
  }

  float invs[4];
#pragma unroll
  for (int j = 0; j < 4; ++j)
    invs[j] = 1.f / ws[OFF_NE + (size_t)b*EE + e0 + j*16 + l15];
#pragma unroll
  for (int j = 0; j < 4; ++j)
#pragma unroll
    for (int q2 = 0; q2 < 4; ++q2)
      simv[w][lq*4 + q2][j*16 + l15] = acc[j][q2] * invs[j];
  // same-wave LDS write->read: lgkmcnt ordering only, no barrier needed
  if (lane < 16) {
    float v[4] = {-FLT_MAX, -FLT_MAX, -FLT_MAX, -FLT_MAX};
    int ix[4] = {0x7fffffff, 0x7fffffff, 0x7fffffff, 0x7fffffff};
#pragma unroll 1
    for (int e = 0; e < 64; ++e) {
      float f = simv[w][lane][e];
      if (f > v[3]) {
        int eg = e0 + e;
        if (f > v[0])      { v[3]=v[2]; ix[3]=ix[2]; v[2]=v[1]; ix[2]=ix[1]; v[1]=v[0]; ix[1]=ix[0]; v[0]=f; ix[0]=eg; }
        else if (f > v[1]) { v[3]=v[2]; ix[3]=ix[2]; v[2]=v[1]; ix[2]=ix[1]; v[1]=f; ix[1]=eg; }
        else if (f > v[2]) { v[3]=v[2]; ix[3]=ix[2]; v[2]=f; ix[2]=eg; }
        else               { v[3]=f; ix[3]=eg; }
      }
    }
    float2* cand = (float2*)(ws + OFF_CAND);
    size_t base = (((size_t)(b*RR + r0 + lane))*64 + eb)*4;
#pragma unroll
    for (int k = 0; k < 4; ++k)
      cand[base + k] = make_float2(v[k], __int_as_float(ix[k]));
  }
}

// ---- merged select: top-4 merge + gather + hh/rh dots, one block per (b,r) ----
__global__ __launch_bounds__(256) void k_select(const float* __restrict__ T,
                                                const float* __restrict__ Sf,
                                                const int* __restrict__ ref_perm,
                                                float* __restrict__ ws) {
  __shared__ float rv[256];
  __shared__ int   ri[256];
  __shared__ int   winIdx;
  __shared__ int   sel[4];
  int br = blockIdx.x;
  int tid = threadIdx.x;
  const float2* cand = (const float2*)(ws + OFF_CAND);
  float2 c0 = cand[(size_t)br*256 + tid];
  float v = c0.x;
  int idx = __float_as_int(c0.y);
  int* outi = (int*)(ws + OFF_TOPK) + (size_t)br*KT;
  for (int k = 0; k < KT; ++k) {
    rv[tid] = v; ri[tid] = idx;
    __syncthreads();
    for (int off = 128; off > 0; off >>= 1) {
      if (tid < off) {
        float v2 = rv[tid+off]; int i2 = ri[tid+off];
        if (v2 > rv[tid] || (v2 == rv[tid] && i2 < ri[tid])) { rv[tid] = v2; ri[tid] = i2; }
      }
      __syncthreads();
    }
    if (tid == 0) { outi[k] = ri[0]; winIdx = ri[0]; sel[k] = ri[0]; }
    __syncthreads();
    if (idx == winIdx) v = -FLT_MAX;
    __syncthreads();
  }

  // phase 2: gather 4 selected rows (group g = k), bf16 store + 3 dots each
  int b = br >> 8, r = br & 255;
  int g = tid >> 6, lane = tid & 63;
  int e = sel[g];
  int rpos = ref_perm[r];
  const float4* src = (const float4*)(T + ((size_t)(b*8 + 1 + 2*(e >> 10))*PP + (e & 1023))*DD);
  const float4* rt  = (const float4*)(T  + ((size_t)(b*8 + 0)*PP + rpos)*DD);
  const float4* rs  = (const float4*)(Sf + ((size_t)(b*4 + 0)*PP + rpos)*DD);
  ushort* uws = (ushort*)(ws + FLOAT_END);
  int rowi = br*KT + g;
  float hh = 0.f, rht = 0.f, rhs = 0.f;
#pragma unroll
  for (int i = 0; i < 4; ++i) {
    int t4 = lane*4 + i;               // 0..255
    float4 h = src[t4];
    *(ushort4*)(uws + wofs(U_SIMH, rowi, t4)) = h4of(h);
    float4 a = rt[t4], c = rs[t4];
    hh  += dot4(h, h);
    rht += dot4(h, a);
    rhs += dot4(h, c);
  }
  hh  += __shfl_down(hh, 32);  hh  += __shfl_down(hh, 16);
  hh  += __shfl_down(hh, 8);   hh  += __shfl_down(hh, 4);
  hh  += __shfl_down(hh, 2);   hh  += __shfl_down(hh, 1);
  rht += __shfl_down(rht, 32); rht += __shfl_down(rht, 16);
  rht += __shfl_down(rht, 8);  rht += __shfl_down(rht, 4);
  rht += __shfl_down(rht, 2);  rht += __shfl_down(rht, 1);
  rhs += __shfl_down(rhs, 32); rhs += __shfl_down(rhs, 16);
  rhs += __shfl_down(rhs, 8);  rhs += __shfl_down(rhs, 4);
  rhs += __shfl_down(rhs, 2);  rhs += __shfl_down(rhs, 1);
  if (lane == 0) {
    ws[OFF_HH + rowi]   = hh;
    ws[OFF_RH_T + rowi] = rht;
    ws[OFF_RH_S + rowi] = rhs;
  }
}

// ---- main fused kernel: BARRIER-FREE, s32 per wave, balanced 512x192 ----
// 1536 wave-tiles; 3 waves/block, 512 blocks = exactly 2 blocks/CU.
// u8 = d&7 (XCD pin); t = (d>>3)*3 + w in [0,192): p = t>>6; s32i = (t&63)>>3;
// r16q = t&7; r16i = rhalf*8 + r16q.
__global__ __launch_bounds__(192) void k_main(float* __restrict__ ws,
                                              double* __restrict__ acc_out) {
  __shared__ float Ct[3][80][17];
  __shared__ float Cs2[3][80][17];
  __shared__ float sb[3];
  const ushort* uws = (const ushort*)(ws + FLOAT_END);

  int d = blockIdx.x;
  int u8 = d & 7, q = d >> 3;        // q 0..63
  int b = u8 >> 1, rhalf = u8 & 1;
  int tid = threadIdx.x;
  int w = tid >> 6, lane = tid & 63;
  int t = q*3 + w;                   // 0..191
  int p = t >> 6;
  int rem = t & 63;
  int s32i = rem >> 3, r16q = rem & 7;
  int z = p*4 + b;
  int r16i = rhalf*8 + r16q;
  int r0 = r16i*16, s0 = s32i*32;

  int l15 = lane & 15, lq = (lane >> 4) & 3;
  int laneoff = l15*32 + ((lq ^ ((l15 >> 1) & 3)))*8;

  // fragment pointers (each contiguous 1 KB per k-step)
  const ushort* pa0; const ushort* pa1; const ushort* pa2; const ushort* pa3;
  const ushort* prt; const ushort* prs;
  const ushort* pbt0; const ushort* pbt1; const ushort* pbs0; const ushort* pbs1;
  {
    size_t gs = (size_t)((b*RR + r0) >> 2);      // simh group base (4 groups)
    pa0 = uws + U_SIMH + (gs + 0)*16384 + laneoff;
    pa1 = uws + U_SIMH + (gs + 1)*16384 + laneoff;
    pa2 = uws + U_SIMH + (gs + 2)*16384 + laneoff;
    pa3 = uws + U_SIMH + (gs + 3)*16384 + laneoff;
    size_t gr = (size_t)((b*RR + r0) >> 4);
    prt = uws + U_REF_T + gr*16384 + laneoff;
    prs = uws + U_REF_S + gr*16384 + laneoff;
    size_t gh = (size_t)((z*SSZ + s0) >> 4);
    pbt0 = uws + U_SH_T + (gh + 0)*16384 + laneoff;
    pbt1 = uws + U_SH_T + (gh + 1)*16384 + laneoff;
    pbs0 = uws + U_SH_S + (gh + 0)*16384 + laneoff;
    pbs1 = uws + U_SH_S + (gh + 1)*16384 + laneoff;
  }

  f32x4 aT0[2], aT1[2], aT2[2], aT3[2], aRT[2];
  f32x4 aS0[2], aS1[2], aS2[2], aS3[2], aRS[2];
#pragma unroll
  for (int h = 0; h < 2; ++h) {
    aT0[h] = aT1[h] = aT2[h] = aT3[h] = aRT[h] = (f32x4){0.f,0.f,0.f,0.f};
    aS0[h] = aS1[h] = aS2[h] = aS3[h] = aRS[h] = (f32x4){0.f,0.f,0.f,0.f};
  }

#pragma unroll 2
  for (int c = 0; c < 32; ++c) {
    int o = c*512;
    short8 bt0 = *(const short8*)(pbt0 + o);
    short8 bt1 = *(const short8*)(pbt1 + o);
    short8 bs0 = *(const short8*)(pbs0 + o);
    short8 bs1 = *(const short8*)(pbs1 + o);
    short8 a0 = *(const short8*)(pa0 + o);
    short8 a1 = *(const short8*)(pa1 + o);
    short8 a2 = *(const short8*)(pa2 + o);
    short8 a3 = *(const short8*)(pa3 + o);
    short8 rt = *(const short8*)(prt + o);
    short8 rs = *(const short8*)(prs + o);
    aT0[0] = MFMA16(a0, bt0, aT0[0]);  aT0[1] = MFMA16(a0, bt1, aT0[1]);
    aT1[0] = MFMA16(a1, bt0, aT1[0]);  aT1[1] = MFMA16(a1, bt1, aT1[1]);
    aT2[0] = MFMA16(a2, bt0, aT2[0]);  aT2[1] = MFMA16(a2, bt1, aT2[1]);
    aT3[0] = MFMA16(a3, bt0, aT3[0]);  aT3[1] = MFMA16(a3, bt1, aT3[1]);
    aRT[0] = MFMA16(rt, bt0, aRT[0]);  aRT[1] = MFMA16(rt, bt1, aRT[1]);
    aS0[0] = MFMA16(a0, bs0, aS0[0]);  aS0[1] = MFMA16(a0, bs1, aS0[1]);
    aS1[0] = MFMA16(a1, bs0, aS1[0]);  aS1[1] = MFMA16(a1, bs1, aS1[1]);
    aS2[0] = MFMA16(a2, bs0, aS2[0]);  aS2[1] = MFMA16(a2, bs1, aS2[1]);
    aS3[0] = MFMA16(a3, bs0, aS3[0]);  aS3[1] = MFMA16(a3, bs1, aS3[1]);
    aRS[0] = MFMA16(rs, bs0, aRS[0]);  aRS[1] = MFMA16(rs, bs1, aRS[1]);
  }

  // per-r scalars (h-independent)
  int rl = lane >> 2, sg = lane & 3;
  int r = r0 + rl;
  float rrt = ws[OFF_RR_T + b*RR + r];
  float rrs = ws[OFF_RR_S + b*RR + r];
  float hhk[4], rhtk[4], rhsk[4], ihr_t[4], ihr_s[4];
#pragma unroll
  for (int k = 0; k < 4; ++k) {
    int idx = (b*RR + r)*KT + k;
    hhk[k]  = ws[OFF_HH + idx];
    rhtk[k] = ws[OFF_RH_T + idx];
    rhsk[k] = ws[OFF_RH_S + idx];
    float nt = sqrtf(fmaxf(hhk[k] - 2.f*rhtk[k] + rrt, 0.f));
    float ns = sqrtf(fmaxf(hhk[k] - 2.f*rhsk[k] + rrs, 0.f));
    ihr_t[k] = 1.f / fmaxf(nt, 1e-8f);
    ihr_s[k] = 1.f / fmaxf(ns, 1e-8f);
  }

  float local = 0.f;
#pragma unroll
  for (int h = 0; h < 2; ++h) {
    // dump half h into per-wave slab (same-wave LDS ordering, no barrier)
#pragma unroll
    for (int q2 = 0; q2 < 4; ++q2) {
      int rg = lq*4 + q2;
      Ct[w][ 0 + rg][l15] = aT0[h][q2];
      Ct[w][16 + rg][l15] = aT1[h][q2];
      Ct[w][32 + rg][l15] = aT2[h][q2];
      Ct[w][48 + rg][l15] = aT3[h][q2];
      Ct[w][64 + rg][l15] = aRT[h][q2];
      Cs2[w][ 0 + rg][l15] = aS0[h][q2];
      Cs2[w][16 + rg][l15] = aS1[h][q2];
      Cs2[w][32 + rg][l15] = aS2[h][q2];
      Cs2[w][48 + rg][l15] = aS3[h][q2];
      Cs2[w][64 + rg][l15] = aRS[h][q2];
    }
#pragma unroll
    for (int j = 0; j < 4; ++j) {
      int sl = sg*4 + j;
      int sidx = z*SSZ + s0 + h*16 + sl;
      float sst = ws[OFF_SS_T + sidx];
      float sss = ws[OFF_SS_S + sidx];
      float srt = Ct[w][64 + rl][sl];
      float srs = Cs2[w][64 + rl][sl];
      float isr_t = 1.f / fmaxf(sqrtf(fmaxf(sst - 2.f*srt + rrt, 0.f)), 1e-8f);
      float isr_s = 1.f / fmaxf(sqrtf(fmaxf(sss - 2.f*srs + rrs, 0.f)), 1e-8f);
#pragma unroll
      for (int k = 0; k < 4; ++k) {
        float sht = Ct[w][rl*4 + k][sl];
        float shs = Cs2[w][rl*4 + k][sl];
        float ish_t = 1.f / fmaxf(sqrtf(fmaxf(sst - 2.f*sht + hhk[k], 0.f)), 1e-8f);
        float ish_s = 1.f / fmaxf(sqrtf(fmaxf(sss - 2.f*shs + hhk[k], 0.f)), 1e-8f);
        float a1t = (sht - rhtk[k] - srt + rrt) * (isr_t * ihr_t[k]);
        float a2t = (srt - sht - rhtk[k] + hhk[k]) * (ihr_t[k] * ish_t);
        float a3t = (rhtk[k] - srt - sht + sst) * (isr_t * ish_t);
        float a1s = (shs - rhsk[k] - srs + rrs) * (isr_s * ihr_s[k]);
        float a2s = (srs - shs - rhsk[k] + hhk[k]) * (ihr_s[k] * ish_s);
        float a3s = (rhsk[k] - srs - shs + sss) * (isr_s * ish_s);
        local += fabsf(a1s - a1t) + fabsf(a2s - a2t) + fabsf(a3s - a3t);
      }
    }
  }

  // block sum over 192 threads (3 waves)
  float v = local;
  v += __shfl_down(v, 32); v += __shfl_down(v, 16);
  v += __shfl_down(v, 8);  v += __shfl_down(v, 4);
  v += __shfl_down(v, 2);  v += __shfl_down(v, 1);
  if (lane == 0) sb[w] = v;
  __syncthreads();
  if (tid == 0) atomicAdd(acc_out, (double)(sb[0] + sb[1] + sb[2]));
}

__global__ void k_final(const double* __restrict__ acc, float* __restrict__ out) {
  out[0] = (float)(acc[0] / 3145728.0);   // 3 * B * R * S * K
}

extern "C" void kernel_launch(void* const* d_in, const int* in_sizes, int n_in,
                              void* d_out, int out_size, void* d_ws, size_t ws_size,
                              hipStream_t stream) {
  const float* T  = (const float*)d_in[0];
  const float* Sf = (const float*)d_in[1];
  const int* ref_perm    = (const int*)d_in[2];
  const int* shared_perm = (const int*)d_in[3];
  float* ws = (float*)d_ws;
  double* acc = (double*)(ws + OFF_ACC);

  hipMemsetAsync(acc, 0, sizeof(double), stream);
  k_prep<<<20480, 256, 0, stream>>>(T, Sf, ref_perm, shared_perm, ws);
  k_sim<<<1024, 256, 0, stream>>>(ws);
  k_select<<<BB*RR, 256, 0, stream>>>(T, Sf, ref_perm, ws);
  k_main<<<512, 192, 0, stream>>>(ws, acc);
  k_final<<<1, 1, 0, stream>>>(acc, (float*)d_out);
}